// Round 5
// baseline (263.221 us; speedup 1.0000x reference)
//
#include <hip/hip_runtime.h>
#include <stdint.h>

#define HW 625              // 25*25
#define NROT 6
#define C_OUT 161
#define OUT_PER_B (C_OUT * HW)   // 100625
#define IN_PER_B  (128 * HW)     // 80000
#define NT 256
#define QF  20000           // floats per heavy quarter (32 channels * 625)
#define NF4 5000            // float4s per quarter
#define CST 629             // obs LDS copy stride; 629 % 4 == 1 -> conflict-free

typedef float f4v __attribute__((ext_vector_type(4)));
typedef float f2v __attribute__((ext_vector_type(2)));

__device__ __forceinline__ void stnt1(float* p, float v) { __builtin_nontemporal_store(v, p); }
__device__ __forceinline__ void stnt2(float* p, float a, float b) {
    f2v v; v.x = a; v.y = b; __builtin_nontemporal_store(v, (f2v*)p);
}
__device__ __forceinline__ void stnt4(float* p, float a, float b, float c, float d) {
    f4v v; v.x = a; v.y = b; v.z = c; v.w = d; __builtin_nontemporal_store(v, (f4v*)p);
}

__global__ __launch_bounds__(NT)
void env_embed(const float* __restrict__ sta, const float* __restrict__ dyn,
               const float* __restrict__ obst, const float* __restrict__ ocur,
               const float* __restrict__ omem, const float* __restrict__ pvis,
               const float* __restrict__ atgt, const float* __restrict__ ptgt,
               const float* __restrict__ lead, const float* __restrict__ foll,
               const int* __restrict__ rots, float* __restrict__ out, const int nb)
{
    const int bid = blockIdx.x;
    const int t = threadIdx.x;
    const int nheavy = 4 * nb;

    if (bid >= nheavy) {
        // ================= small channels 128..160, one block per batch =========
        const int b = bid - nheavy;
        const int rot = rots[b];             // block-uniform
        const int bHW = b * HW;
        float* const out_b = out + (size_t)b * OUT_PER_B;

        for (int p = t; p < HW; p += NT) {
            const float obs = omem[bHW + p];
            float* const ob = out_b + p;

            stnt1(ob + 128 * HW, obst[bHW + p] * obs);
            stnt1(ob + 129 * HW, ocur[bHW + p] * obs);
            stnt1(ob + 130 * HW, obs * obs);
            stnt1(ob + 138 * HW, lead[bHW + p] * obs);
            stnt1(ob + 139 * HW, foll[bHW + p] * obs);

            float s_pv = 0.f, s_at = 0.f, s_pt = 0.f;
            #pragma unroll
            for (int r = 0; r < NROT; ++r) { // iterate SOURCE rotation
                const float pv = pvis[(b * NROT + r) * HW + p];
                const float at = atgt[(b * NROT + r) * HW + p];
                const float pt = ptgt[(b * NROT + r) * HW + p];
                s_pv += pv; s_at += at; s_pt += pt;
                int jj = r + rot; if (jj >= NROT) jj -= NROT;   // dest channel
                stnt1(ob + (131 + jj) * HW, pv * 0.5f * obs);
                stnt1(ob + (140 + jj) * HW, at * 0.5f * obs);
                stnt1(ob + (146 + jj) * HW, pt * obs);
            }
            stnt1(ob + 137 * HW, s_pv * obs);
            stnt1(ob + 152 * HW, s_at * 0.5f * obs);
            stnt1(ob + 153 * HW, s_pt * obs);
            stnt1(ob + 154 * HW, 1.0f);
            #pragma unroll
            for (int jj = 0; jj < NROT; ++jj)
                stnt1(ob + (155 + jj) * HW, (jj == rot) ? 1.0f : 0.0f);
        }
        return;
    }

    // ================= heavy channels: 4 blocks per batch, 32 channels each ====
    const int b = bid >> 2;
    const int j = bid & 3;

    __shared__ float lobs[4 * CST];          // 4 bank-shifted copies of obs plane
    for (int p = t; p < HW; p += NT) {
        const float v = omem[b * HW + p];
        lobs[p] = v; lobs[CST + p] = v; lobs[2 * CST + p] = v; lobs[3 * CST + p] = v;
    }
    __syncthreads();

    const float* const sb = sta + (size_t)b * IN_PER_B + j * QF;   // 16B-aligned
    const float* const db = dyn + (size_t)b * IN_PER_B + j * QF;
    float* const ob = out + (size_t)b * OUT_PER_B + j * QF;        // align mod4 = b%4
    const float* const L = lobs + ((t >> 3) & 3) * CST;
    const int amode = b & 3;                 // block-uniform store-alignment mode

#define OBS4(Q, O0, O1, O2, O3) {                                  \
        int qq = (Q);                                              \
        O0 = L[qq]; qq = (qq == HW - 1) ? 0 : qq + 1;              \
        O1 = L[qq]; qq = (qq == HW - 1) ? 0 : qq + 1;              \
        O2 = L[qq]; qq = (qq == HW - 1) ? 0 : qq + 1;              \
        O3 = L[qq]; }

#define STORE4(PO, R0, R1, R2, R3) {                               \
        if (amode == 0)       stnt4((PO), R0, R1, R2, R3);         \
        else if (amode == 2) { stnt2((PO), R0, R1); stnt2((PO) + 2, R2, R3); } \
        else { stnt1((PO), R0); stnt1((PO) + 1, R1);               \
               stnt1((PO) + 2, R2); stnt1((PO) + 3, R3); } }

#define COMPUTE_STORE(IDX, S4, D4) {                               \
        float o0, o1, o2, o3;                                      \
        OBS4((IDX) % HW, o0, o1, o2, o3);                          \
        const float r0 = (S4.x + D4.x) * o0, r1 = (S4.y + D4.y) * o1; \
        const float r2 = (S4.z + D4.z) * o2, r3 = (S4.w + D4.w) * o3; \
        STORE4(ob + (IDX), r0, r1, r2, r3); }

    int k = t;
    for (; k + 3 * NT < NF4; k += 4 * NT) {
        const int i0 = 4 * k, i1 = 4 * (k + NT), i2 = 4 * (k + 2 * NT), i3 = 4 * (k + 3 * NT);
        // issue all 8 global loads, then FENCE the scheduler so it cannot sink
        // them to just-before-use (round-4 failure mode: VGPR_Count=36 proved
        // the 8-deep cluster never existed in the ISA).
        const f4v s0 = *(const f4v*)(sb + i0);
        const f4v d0 = *(const f4v*)(db + i0);
        const f4v s1 = *(const f4v*)(sb + i1);
        const f4v d1 = *(const f4v*)(db + i1);
        const f4v s2 = *(const f4v*)(sb + i2);
        const f4v d2 = *(const f4v*)(db + i2);
        const f4v s3 = *(const f4v*)(sb + i3);
        const f4v d3 = *(const f4v*)(db + i3);
        __builtin_amdgcn_sched_barrier(0);   // all 8 loads issued before anything below

        COMPUTE_STORE(i0, s0, d0);
        COMPUTE_STORE(i1, s1, d1);
        COMPUTE_STORE(i2, s2, d2);
        COMPUTE_STORE(i3, s3, d3);
    }
    for (; k < NF4; k += NT) {
        const int i0 = 4 * k;
        const f4v s0 = *(const f4v*)(sb + i0);
        const f4v d0 = *(const f4v*)(db + i0);
        COMPUTE_STORE(i0, s0, d0);
    }
#undef OBS4
#undef STORE4
#undef COMPUTE_STORE
}

extern "C" void kernel_launch(void* const* d_in, const int* in_sizes, int n_in,
                              void* d_out, int out_size, void* d_ws, size_t ws_size,
                              hipStream_t stream) {
    const float* sta  = (const float*)d_in[0];
    const float* dyn  = (const float*)d_in[1];
    const float* obst = (const float*)d_in[2];
    const float* ocur = (const float*)d_in[3];
    const float* omem = (const float*)d_in[4];
    const float* pvis = (const float*)d_in[5];
    const float* atgt = (const float*)d_in[6];
    const float* ptgt = (const float*)d_in[7];
    const float* lead = (const float*)d_in[8];
    const float* foll = (const float*)d_in[9];
    const int*   rots = (const int*)d_in[10];
    float* out = (float*)d_out;

    const int nb = in_sizes[10];             // batch count (1024)

    hipLaunchKernelGGL(env_embed, dim3(5 * nb), dim3(NT), 0, stream,
                       sta, dyn, obst, ocur, omem, pvis, atgt, ptgt,
                       lead, foll, rots, out, nb);
}

// Round 6
// 250.351 us; speedup vs baseline: 1.0514x; 1.0514x over previous
//
#include <hip/hip_runtime.h>
#include <stdint.h>

#define HW 625              // 25*25
#define NROT 6
#define C_OUT 161
#define OUT_PER_B (C_OUT * HW)   // 100625
#define IN_PER_B  (128 * HW)     // 80000
#define NT 256
#define QF  20000           // floats per heavy quarter (32 channels * 625)
#define NF4 5000            // float4s per quarter
#define CST 629             // obs LDS copy stride; 629 % 4 == 1 -> conflict-free

typedef float f4v __attribute__((ext_vector_type(4)));

__global__ __launch_bounds__(NT)
void env_embed(const float* __restrict__ sta, const float* __restrict__ dyn,
               const float* __restrict__ obst, const float* __restrict__ ocur,
               const float* __restrict__ omem, const float* __restrict__ pvis,
               const float* __restrict__ atgt, const float* __restrict__ ptgt,
               const float* __restrict__ lead, const float* __restrict__ foll,
               const int* __restrict__ rots, float* __restrict__ out, const int nb)
{
    const int bid = blockIdx.x;
    const int t = threadIdx.x;
    const int nheavy = 4 * nb;

    if (bid >= nheavy) {
        // ================= small channels 128..160, one block per batch =========
        const int b = bid - nheavy;
        const int rot = rots[b];             // block-uniform
        const int bHW = b * HW;
        float* const out_b = out + (size_t)b * OUT_PER_B;

        for (int p = t; p < HW; p += NT) {
            const float obs = omem[bHW + p];
            float* const ob = out_b + p;

            ob[128 * HW] = obst[bHW + p] * obs;
            ob[129 * HW] = ocur[bHW + p] * obs;
            ob[130 * HW] = obs * obs;
            ob[138 * HW] = lead[bHW + p] * obs;
            ob[139 * HW] = foll[bHW + p] * obs;

            float s_pv = 0.f, s_at = 0.f, s_pt = 0.f;
            #pragma unroll
            for (int r = 0; r < NROT; ++r) { // iterate SOURCE rotation
                const float pv = pvis[(b * NROT + r) * HW + p];
                const float at = atgt[(b * NROT + r) * HW + p];
                const float pt = ptgt[(b * NROT + r) * HW + p];
                s_pv += pv; s_at += at; s_pt += pt;
                int jj = r + rot; if (jj >= NROT) jj -= NROT;   // dest channel
                ob[(131 + jj) * HW] = pv * 0.5f * obs;
                ob[(140 + jj) * HW] = at * 0.5f * obs;
                ob[(146 + jj) * HW] = pt * obs;
            }
            ob[137 * HW] = s_pv * obs;
            ob[152 * HW] = s_at * 0.5f * obs;
            ob[153 * HW] = s_pt * obs;
            ob[154 * HW] = 1.0f;
            #pragma unroll
            for (int jj = 0; jj < NROT; ++jj)
                ob[(155 + jj) * HW] = (jj == rot) ? 1.0f : 0.0f;
        }
        return;
    }

    // ================= heavy channels: 4 blocks per batch, 32 channels each ====
    const int b = bid >> 2;
    const int j = bid & 3;

    __shared__ float lobs[4 * CST];          // 4 bank-shifted copies of obs plane
    for (int p = t; p < HW; p += NT) {
        const float v = omem[b * HW + p];
        lobs[p] = v; lobs[CST + p] = v; lobs[2 * CST + p] = v; lobs[3 * CST + p] = v;
    }
    __syncthreads();

    const float* const sb = sta + (size_t)b * IN_PER_B + j * QF;   // 16B-aligned
    const float* const db = dyn + (size_t)b * IN_PER_B + j * QF;
    float* const ob = out + (size_t)b * OUT_PER_B + j * QF;        // align mod4 = b%4
    const float* const L = lobs + ((t >> 3) & 3) * CST;
    const int amode = b & 3;                 // block-uniform store-alignment mode

#define OBS4(Q, O0, O1, O2, O3) {                                  \
        int qq = (Q);                                              \
        O0 = L[qq]; qq = (qq == HW - 1) ? 0 : qq + 1;              \
        O1 = L[qq]; qq = (qq == HW - 1) ? 0 : qq + 1;              \
        O2 = L[qq]; qq = (qq == HW - 1) ? 0 : qq + 1;              \
        O3 = L[qq]; }

#define STORE4(PO, R0, R1, R2, R3) {                               \
        if (amode == 0)       *(float4*)(PO) = make_float4(R0, R1, R2, R3); \
        else if (amode == 2) { *(float2*)(PO) = make_float2(R0, R1);        \
                               *(float2*)((PO) + 2) = make_float2(R2, R3); }\
        else { (PO)[0] = R0; (PO)[1] = R1; (PO)[2] = R2; (PO)[3] = R3; } }

#define COMPUTE_STORE(IDX, S4, D4) {                               \
        float o0, o1, o2, o3;                                      \
        OBS4((IDX) % HW, o0, o1, o2, o3);                          \
        const float r0 = (S4.x + D4.x) * o0, r1 = (S4.y + D4.y) * o1; \
        const float r2 = (S4.z + D4.z) * o2, r3 = (S4.w + D4.w) * o3; \
        STORE4(ob + (IDX), r0, r1, r2, r3); }

    int k = t;
    for (; k + 3 * NT < NF4; k += 4 * NT) {
        const int i0 = 4 * k, i1 = 4 * (k + NT), i2 = 4 * (k + 2 * NT), i3 = 4 * (k + 3 * NT);
        // Issue all 8 loads, then TIE them with an inline-asm use. Unlike
        // sched_barrier(0) (IntrNoMem -> IR passes sank the loads anyway,
        // rounds 4/5: VGPR_Count=36), this is a real use of the 8 values:
        // nothing can sink the loads below it. Burst-8 MLP per wave.
        f4v s0 = *(const f4v*)(sb + i0);
        f4v d0 = *(const f4v*)(db + i0);
        f4v s1 = *(const f4v*)(sb + i1);
        f4v d1 = *(const f4v*)(db + i1);
        f4v s2 = *(const f4v*)(sb + i2);
        f4v d2 = *(const f4v*)(db + i2);
        f4v s3 = *(const f4v*)(sb + i3);
        f4v d3 = *(const f4v*)(db + i3);
        asm volatile("" : "+v"(s0), "+v"(d0), "+v"(s1), "+v"(d1),
                          "+v"(s2), "+v"(d2), "+v"(s3), "+v"(d3));

        COMPUTE_STORE(i0, s0, d0);
        COMPUTE_STORE(i1, s1, d1);
        COMPUTE_STORE(i2, s2, d2);
        COMPUTE_STORE(i3, s3, d3);
    }
    for (; k < NF4; k += NT) {
        const int i0 = 4 * k;
        const f4v s0 = *(const f4v*)(sb + i0);
        const f4v d0 = *(const f4v*)(db + i0);
        COMPUTE_STORE(i0, s0, d0);
    }
#undef OBS4
#undef STORE4
#undef COMPUTE_STORE
}

extern "C" void kernel_launch(void* const* d_in, const int* in_sizes, int n_in,
                              void* d_out, int out_size, void* d_ws, size_t ws_size,
                              hipStream_t stream) {
    const float* sta  = (const float*)d_in[0];
    const float* dyn  = (const float*)d_in[1];
    const float* obst = (const float*)d_in[2];
    const float* ocur = (const float*)d_in[3];
    const float* omem = (const float*)d_in[4];
    const float* pvis = (const float*)d_in[5];
    const float* atgt = (const float*)d_in[6];
    const float* ptgt = (const float*)d_in[7];
    const float* lead = (const float*)d_in[8];
    const float* foll = (const float*)d_in[9];
    const int*   rots = (const int*)d_in[10];
    float* out = (float*)d_out;

    const int nb = in_sizes[10];             // batch count (1024)

    hipLaunchKernelGGL(env_embed, dim3(5 * nb), dim3(NT), 0, stream,
                       sta, dyn, obst, ocur, omem, pvis, atgt, ptgt,
                       lead, foll, rots, out, nb);
}

// Round 7
// 244.434 us; speedup vs baseline: 1.0769x; 1.0242x over previous
//
#include <hip/hip_runtime.h>
#include <stdint.h>

#define HW 625              // 25*25
#define NROT 6
#define C_OUT 161
#define OUT_PER_B (C_OUT * HW)   // 100625
#define IN_PER_B  (128 * HW)     // 80000
#define NT 256
#define QF  20000           // floats per heavy quarter (32 channels * 625)
#define NF4 5000            // float4s per quarter
#define CST 629             // obs LDS copy stride; 629 % 4 == 1 -> conflict-free

typedef float f4v __attribute__((ext_vector_type(4)));

__global__ __launch_bounds__(NT)
void env_embed(const float* __restrict__ sta, const float* __restrict__ dyn,
               const float* __restrict__ obst, const float* __restrict__ ocur,
               const float* __restrict__ omem, const float* __restrict__ pvis,
               const float* __restrict__ atgt, const float* __restrict__ ptgt,
               const float* __restrict__ lead, const float* __restrict__ foll,
               const int* __restrict__ rots, float* __restrict__ out, const int nb)
{
    const int bid = blockIdx.x;
    const int t = threadIdx.x;
    // Interleaved dispatch: every 5th block is a small-channel block, so the
    // scalar latency-bound small work overlaps the heavy stream for the whole
    // kernel instead of forming a ~60us serial tail (rounds 2-6: smalls pooled
    // at one end -> flat 270us regardless of all inner-loop changes).
    const int q = bid / 5;
    const int r = bid - 5 * q;

    if (r == 4) {
        // ================= small channels 128..160, one block per batch =========
        const int b = q;
        const int rot = rots[b];             // block-uniform
        const int bHW = b * HW;
        float* const out_b = out + (size_t)b * OUT_PER_B;

        for (int p = t; p < HW; p += NT) {
            const float obs = omem[bHW + p];
            float* const ob = out_b + p;

            ob[128 * HW] = obst[bHW + p] * obs;
            ob[129 * HW] = ocur[bHW + p] * obs;
            ob[130 * HW] = obs * obs;
            ob[138 * HW] = lead[bHW + p] * obs;
            ob[139 * HW] = foll[bHW + p] * obs;

            float s_pv = 0.f, s_at = 0.f, s_pt = 0.f;
            #pragma unroll
            for (int rr = 0; rr < NROT; ++rr) { // iterate SOURCE rotation
                const float pv = pvis[(b * NROT + rr) * HW + p];
                const float at = atgt[(b * NROT + rr) * HW + p];
                const float pt = ptgt[(b * NROT + rr) * HW + p];
                s_pv += pv; s_at += at; s_pt += pt;
                int jj = rr + rot; if (jj >= NROT) jj -= NROT;   // dest channel
                ob[(131 + jj) * HW] = pv * 0.5f * obs;
                ob[(140 + jj) * HW] = at * 0.5f * obs;
                ob[(146 + jj) * HW] = pt * obs;
            }
            ob[137 * HW] = s_pv * obs;
            ob[152 * HW] = s_at * 0.5f * obs;
            ob[153 * HW] = s_pt * obs;
            ob[154 * HW] = 1.0f;
            #pragma unroll
            for (int jj = 0; jj < NROT; ++jj)
                ob[(155 + jj) * HW] = (jj == rot) ? 1.0f : 0.0f;
        }
        return;
    }

    // ================= heavy channels: 4 blocks per batch, 32 channels each ====
    const int b = q;
    const int j = r;

    __shared__ float lobs[4 * CST];          // 4 bank-shifted copies of obs plane
    for (int p = t; p < HW; p += NT) {
        const float v = omem[b * HW + p];
        lobs[p] = v; lobs[CST + p] = v; lobs[2 * CST + p] = v; lobs[3 * CST + p] = v;
    }
    __syncthreads();

    const float* const sb = sta + (size_t)b * IN_PER_B + j * QF;   // 16B-aligned
    const float* const db = dyn + (size_t)b * IN_PER_B + j * QF;
    float* const ob = out + (size_t)b * OUT_PER_B + j * QF;        // align mod4 = b%4
    const float* const L = lobs + ((t >> 3) & 3) * CST;
    const int amode = b & 3;                 // block-uniform store-alignment mode

#define OBS4(Q, O0, O1, O2, O3) {                                  \
        int qq = (Q);                                              \
        O0 = L[qq]; qq = (qq == HW - 1) ? 0 : qq + 1;              \
        O1 = L[qq]; qq = (qq == HW - 1) ? 0 : qq + 1;              \
        O2 = L[qq]; qq = (qq == HW - 1) ? 0 : qq + 1;              \
        O3 = L[qq]; }

#define STORE4(PO, R0, R1, R2, R3) {                               \
        if (amode == 0)       *(float4*)(PO) = make_float4(R0, R1, R2, R3); \
        else if (amode == 2) { *(float2*)(PO) = make_float2(R0, R1);        \
                               *(float2*)((PO) + 2) = make_float2(R2, R3); }\
        else { (PO)[0] = R0; (PO)[1] = R1; (PO)[2] = R2; (PO)[3] = R3; } }

#define COMPUTE_STORE(IDX, S4, D4) {                               \
        float o0, o1, o2, o3;                                      \
        OBS4((IDX) % HW, o0, o1, o2, o3);                          \
        const float r0 = (S4.x + D4.x) * o0, r1 = (S4.y + D4.y) * o1; \
        const float r2 = (S4.z + D4.z) * o2, r3 = (S4.w + D4.w) * o3; \
        STORE4(ob + (IDX), r0, r1, r2, r3); }

    int k = t;
    for (; k + 3 * NT < NF4; k += 4 * NT) {
        const int i0 = 4 * k, i1 = 4 * (k + NT), i2 = 4 * (k + 2 * NT), i3 = 4 * (k + 3 * NT);
        f4v s0 = *(const f4v*)(sb + i0);
        f4v d0 = *(const f4v*)(db + i0);
        f4v s1 = *(const f4v*)(sb + i1);
        f4v d1 = *(const f4v*)(db + i1);
        f4v s2 = *(const f4v*)(sb + i2);
        f4v d2 = *(const f4v*)(db + i2);
        f4v s3 = *(const f4v*)(sb + i3);
        f4v d3 = *(const f4v*)(db + i3);
        asm volatile("" : "+v"(s0), "+v"(d0), "+v"(s1), "+v"(d1),
                          "+v"(s2), "+v"(d2), "+v"(s3), "+v"(d3));

        COMPUTE_STORE(i0, s0, d0);
        COMPUTE_STORE(i1, s1, d1);
        COMPUTE_STORE(i2, s2, d2);
        COMPUTE_STORE(i3, s3, d3);
    }
    for (; k < NF4; k += NT) {
        const int i0 = 4 * k;
        const f4v s0 = *(const f4v*)(sb + i0);
        const f4v d0 = *(const f4v*)(db + i0);
        COMPUTE_STORE(i0, s0, d0);
    }
#undef OBS4
#undef STORE4
#undef COMPUTE_STORE
}

extern "C" void kernel_launch(void* const* d_in, const int* in_sizes, int n_in,
                              void* d_out, int out_size, void* d_ws, size_t ws_size,
                              hipStream_t stream) {
    const float* sta  = (const float*)d_in[0];
    const float* dyn  = (const float*)d_in[1];
    const float* obst = (const float*)d_in[2];
    const float* ocur = (const float*)d_in[3];
    const float* omem = (const float*)d_in[4];
    const float* pvis = (const float*)d_in[5];
    const float* atgt = (const float*)d_in[6];
    const float* ptgt = (const float*)d_in[7];
    const float* lead = (const float*)d_in[8];
    const float* foll = (const float*)d_in[9];
    const int*   rots = (const int*)d_in[10];
    float* out = (float*)d_out;

    const int nb = in_sizes[10];             // batch count (1024)

    hipLaunchKernelGGL(env_embed, dim3(5 * nb), dim3(NT), 0, stream,
                       sta, dyn, obst, ocur, omem, pvis, atgt, ptgt,
                       lead, foll, rots, out, nb);
}

// Round 8
// 243.946 us; speedup vs baseline: 1.0790x; 1.0020x over previous
//
#include <hip/hip_runtime.h>
#include <stdint.h>

#define HW 625              // 25*25
#define NROT 6
#define C_OUT 161
#define OUT_PER_B (C_OUT * HW)   // 100625
#define IN_PER_B  (128 * HW)     // 80000
#define NT 256
#define QF  20000           // floats per heavy quarter (32 channels * 625)
#define NF4 5000            // float4s per quarter
#define CST 629             // obs LDS copy stride; 629 % 4 == 1 -> conflict-free

typedef float f4v __attribute__((ext_vector_type(4)));
typedef float f4u __attribute__((ext_vector_type(4), aligned(4)));  // 4B-aligned vector store

__global__ __launch_bounds__(NT)
void env_embed(const float* __restrict__ sta, const float* __restrict__ dyn,
               const float* __restrict__ obst, const float* __restrict__ ocur,
               const float* __restrict__ omem, const float* __restrict__ pvis,
               const float* __restrict__ atgt, const float* __restrict__ ptgt,
               const float* __restrict__ lead, const float* __restrict__ foll,
               const int* __restrict__ rots, float* __restrict__ out, const int nb)
{
    const int bid = blockIdx.x;
    const int t = threadIdx.x;
    // Interleaved dispatch (round 7, neutral but harmless): every 5th block is
    // a small-channel block.
    const int q = bid / 5;
    const int r = bid - 5 * q;

    if (r == 4) {
        // ================= small channels 128..160, one block per batch =========
        const int b = q;
        const int rot = rots[b];             // block-uniform
        const int bHW = b * HW;
        float* const out_b = out + (size_t)b * OUT_PER_B;

        for (int p = t; p < HW; p += NT) {
            const float obs = omem[bHW + p];
            float* const ob = out_b + p;

            ob[128 * HW] = obst[bHW + p] * obs;
            ob[129 * HW] = ocur[bHW + p] * obs;
            ob[130 * HW] = obs * obs;
            ob[138 * HW] = lead[bHW + p] * obs;
            ob[139 * HW] = foll[bHW + p] * obs;

            float s_pv = 0.f, s_at = 0.f, s_pt = 0.f;
            #pragma unroll
            for (int rr = 0; rr < NROT; ++rr) { // iterate SOURCE rotation
                const float pv = pvis[(b * NROT + rr) * HW + p];
                const float at = atgt[(b * NROT + rr) * HW + p];
                const float pt = ptgt[(b * NROT + rr) * HW + p];
                s_pv += pv; s_at += at; s_pt += pt;
                int jj = rr + rot; if (jj >= NROT) jj -= NROT;   // dest channel
                ob[(131 + jj) * HW] = pv * 0.5f * obs;
                ob[(140 + jj) * HW] = at * 0.5f * obs;
                ob[(146 + jj) * HW] = pt * obs;
            }
            ob[137 * HW] = s_pv * obs;
            ob[152 * HW] = s_at * 0.5f * obs;
            ob[153 * HW] = s_pt * obs;
            ob[154 * HW] = 1.0f;
            #pragma unroll
            for (int jj = 0; jj < NROT; ++jj)
                ob[(155 + jj) * HW] = (jj == rot) ? 1.0f : 0.0f;
        }
        return;
    }

    // ================= heavy channels: 4 blocks per batch, 32 channels each ====
    const int b = q;
    const int j = r;

    __shared__ float lobs[4 * CST];          // 4 bank-shifted copies of obs plane
    for (int p = t; p < HW; p += NT) {
        const float v = omem[b * HW + p];
        lobs[p] = v; lobs[CST + p] = v; lobs[2 * CST + p] = v; lobs[3 * CST + p] = v;
    }
    __syncthreads();

    const float* const sb = sta + (size_t)b * IN_PER_B + j * QF;   // 16B-aligned
    const float* const db = dyn + (size_t)b * IN_PER_B + j * QF;
    float* const ob = out + (size_t)b * OUT_PER_B + j * QF;        // 4B-aligned only
    const float* const L = lobs + ((t >> 3) & 3) * CST;

#define OBS4(Q, O0, O1, O2, O3) {                                  \
        int qq = (Q);                                              \
        O0 = L[qq]; qq = (qq == HW - 1) ? 0 : qq + 1;              \
        O1 = L[qq]; qq = (qq == HW - 1) ? 0 : qq + 1;              \
        O2 = L[qq]; qq = (qq == HW - 1) ? 0 : qq + 1;              \
        O3 = L[qq]; }

    // Single unaligned-capable dwordx4 store: gfx950 global_store_dwordx4 is
    // legal at 4B alignment (HW splits at 128B boundaries). Replaces the
    // round-2..7 amode branch (50% of blocks did 4 scalar stores, 25% 2x
    // float2 -> 2.75x minimum store-instruction count).
#define STORE4(PO, R0, R1, R2, R3) {                               \
        f4u v; v.x = R0; v.y = R1; v.z = R2; v.w = R3;             \
        *(f4u*)(PO) = v; }

#define COMPUTE_STORE(IDX, S4, D4) {                               \
        float o0, o1, o2, o3;                                      \
        OBS4((IDX) % HW, o0, o1, o2, o3);                          \
        const float r0 = (S4.x + D4.x) * o0, r1 = (S4.y + D4.y) * o1; \
        const float r2 = (S4.z + D4.z) * o2, r3 = (S4.w + D4.w) * o3; \
        STORE4(ob + (IDX), r0, r1, r2, r3); }

    int k = t;
    for (; k + 3 * NT < NF4; k += 4 * NT) {
        const int i0 = 4 * k, i1 = 4 * (k + NT), i2 = 4 * (k + 2 * NT), i3 = 4 * (k + 3 * NT);
        f4v s0 = *(const f4v*)(sb + i0);
        f4v d0 = *(const f4v*)(db + i0);
        f4v s1 = *(const f4v*)(sb + i1);
        f4v d1 = *(const f4v*)(db + i1);
        f4v s2 = *(const f4v*)(sb + i2);
        f4v d2 = *(const f4v*)(db + i2);
        f4v s3 = *(const f4v*)(sb + i3);
        f4v d3 = *(const f4v*)(db + i3);
        asm volatile("" : "+v"(s0), "+v"(d0), "+v"(s1), "+v"(d1),
                          "+v"(s2), "+v"(d2), "+v"(s3), "+v"(d3));

        COMPUTE_STORE(i0, s0, d0);
        COMPUTE_STORE(i1, s1, d1);
        COMPUTE_STORE(i2, s2, d2);
        COMPUTE_STORE(i3, s3, d3);
    }
    for (; k < NF4; k += NT) {
        const int i0 = 4 * k;
        const f4v s0 = *(const f4v*)(sb + i0);
        const f4v d0 = *(const f4v*)(db + i0);
        COMPUTE_STORE(i0, s0, d0);
    }
#undef OBS4
#undef STORE4
#undef COMPUTE_STORE
}

extern "C" void kernel_launch(void* const* d_in, const int* in_sizes, int n_in,
                              void* d_out, int out_size, void* d_ws, size_t ws_size,
                              hipStream_t stream) {
    const float* sta  = (const float*)d_in[0];
    const float* dyn  = (const float*)d_in[1];
    const float* obst = (const float*)d_in[2];
    const float* ocur = (const float*)d_in[3];
    const float* omem = (const float*)d_in[4];
    const float* pvis = (const float*)d_in[5];
    const float* atgt = (const float*)d_in[6];
    const float* ptgt = (const float*)d_in[7];
    const float* lead = (const float*)d_in[8];
    const float* foll = (const float*)d_in[9];
    const int*   rots = (const int*)d_in[10];
    float* out = (float*)d_out;

    const int nb = in_sizes[10];             // batch count (1024)

    hipLaunchKernelGGL(env_embed, dim3(5 * nb), dim3(NT), 0, stream,
                       sta, dyn, obst, ocur, omem, pvis, atgt, ptgt,
                       lead, foll, rots, out, nb);
}

// Round 9
// 236.973 us; speedup vs baseline: 1.1108x; 1.0294x over previous
//
#include <hip/hip_runtime.h>
#include <stdint.h>

#define HW 625              // 25*25
#define NROT 6
#define C_OUT 161
#define OUT_PER_B (C_OUT * HW)   // 100625
#define IN_PER_B  (128 * HW)     // 80000
#define NT 256
#define QF  20000           // floats per heavy quarter (32 channels * 625)
#define NF4 5000            // float4s per quarter
#define CHUNK 1024          // float4s per paced chunk (4/thread)
#define NCH 4               // full chunks; tail = 5000-4096 = 904 f4, barrier-free
#define CST 629             // obs LDS copy stride; 629 % 4 == 1 -> conflict-free

typedef float f4v __attribute__((ext_vector_type(4)));
typedef float f4u __attribute__((ext_vector_type(4), aligned(4)));  // 4B-aligned vector store

__global__ __launch_bounds__(NT)
void env_embed(const float* __restrict__ sta, const float* __restrict__ dyn,
               const float* __restrict__ obst, const float* __restrict__ ocur,
               const float* __restrict__ omem, const float* __restrict__ pvis,
               const float* __restrict__ atgt, const float* __restrict__ ptgt,
               const float* __restrict__ lead, const float* __restrict__ foll,
               const int* __restrict__ rots, float* __restrict__ out, const int nb)
{
    const int bid = blockIdx.x;
    const int t = threadIdx.x;
    // Interleaved dispatch: every 5th block is a small-channel block.
    const int q = bid / 5;
    const int r = bid - 5 * q;

    if (r == 4) {
        // ================= small channels 128..160, one block per batch =========
        const int b = q;
        const int rot = rots[b];             // block-uniform
        const int bHW = b * HW;
        float* const out_b = out + (size_t)b * OUT_PER_B;

        for (int p = t; p < HW; p += NT) {
            const float obs = omem[bHW + p];
            float* const ob = out_b + p;

            ob[128 * HW] = obst[bHW + p] * obs;
            ob[129 * HW] = ocur[bHW + p] * obs;
            ob[130 * HW] = obs * obs;
            ob[138 * HW] = lead[bHW + p] * obs;
            ob[139 * HW] = foll[bHW + p] * obs;

            float s_pv = 0.f, s_at = 0.f, s_pt = 0.f;
            #pragma unroll
            for (int rr = 0; rr < NROT; ++rr) { // iterate SOURCE rotation
                const float pv = pvis[(b * NROT + rr) * HW + p];
                const float at = atgt[(b * NROT + rr) * HW + p];
                const float pt = ptgt[(b * NROT + rr) * HW + p];
                s_pv += pv; s_at += at; s_pt += pt;
                int jj = rr + rot; if (jj >= NROT) jj -= NROT;   // dest channel
                ob[(131 + jj) * HW] = pv * 0.5f * obs;
                ob[(140 + jj) * HW] = at * 0.5f * obs;
                ob[(146 + jj) * HW] = pt * obs;
            }
            ob[137 * HW] = s_pv * obs;
            ob[152 * HW] = s_at * 0.5f * obs;
            ob[153 * HW] = s_pt * obs;
            ob[154 * HW] = 1.0f;
            #pragma unroll
            for (int jj = 0; jj < NROT; ++jj)
                ob[(155 + jj) * HW] = (jj == rot) ? 1.0f : 0.0f;
        }
        return;
    }

    // ================= heavy channels: 4 blocks per batch, 32 channels each ====
    const int b = q;
    const int j = r;

    __shared__ float lobs[4 * CST];          // 4 bank-shifted copies of obs plane
    for (int p = t; p < HW; p += NT) {
        const float v = omem[b * HW + p];
        lobs[p] = v; lobs[CST + p] = v; lobs[2 * CST + p] = v; lobs[3 * CST + p] = v;
    }
    __syncthreads();                         // real data dependence on lobs

    const float* const sb = sta + (size_t)b * IN_PER_B + j * QF;   // 16B-aligned
    const float* const db = dyn + (size_t)b * IN_PER_B + j * QF;
    float* const ob = out + (size_t)b * OUT_PER_B + j * QF;        // 4B-aligned only
    const float* const L = lobs + ((t >> 3) & 3) * CST;

#define OBS4(Q, O0, O1, O2, O3) {                                  \
        int qq = (Q);                                              \
        O0 = L[qq]; qq = (qq == HW - 1) ? 0 : qq + 1;              \
        O1 = L[qq]; qq = (qq == HW - 1) ? 0 : qq + 1;              \
        O2 = L[qq]; qq = (qq == HW - 1) ? 0 : qq + 1;              \
        O3 = L[qq]; }

#define STORE4(PO, R0, R1, R2, R3) {                               \
        f4u v; v.x = R0; v.y = R1; v.z = R2; v.w = R3;             \
        *(f4u*)(PO) = v; }

    // ---- Paced pipeline over 4 uniform chunks (barrier legal: trip count and
    // branch conditions are thread-invariant; barrier guards no shared data,
    // it only phase-aligns the 4 waves so stores burst while next loads fly).
    f4v sA[4], dA[4];
    #pragma unroll
    for (int u = 0; u < 4; ++u) {            // prologue: loads of chunk 0
        const int i = (u * NT + t) * 4;
        sA[u] = *(const f4v*)(sb + i);
        dA[u] = *(const f4v*)(db + i);
    }

    for (int c = 0; c < NCH; ++c) {
        f4v sN[4], dN[4];
        if (c + 1 < NCH) {                   // issue chunk c+1 loads FIRST
            #pragma unroll
            for (int u = 0; u < 4; ++u) {
                const int i = ((c + 1) * CHUNK + u * NT + t) * 4;
                sN[u] = *(const f4v*)(sb + i);
                dN[u] = *(const f4v*)(db + i);
            }
            asm volatile("" : "+v"(sN[0]), "+v"(dN[0]), "+v"(sN[1]), "+v"(dN[1]),
                              "+v"(sN[2]), "+v"(dN[2]), "+v"(sN[3]), "+v"(dN[3]));
        }

        f4v rr[4];
        #pragma unroll
        for (int u = 0; u < 4; ++u) {        // compute chunk c (counted vmcnt wait)
            const int idx = (c * CHUNK + u * NT + t) * 4;
            float o0, o1, o2, o3;
            OBS4(idx % HW, o0, o1, o2, o3);
            rr[u].x = (sA[u].x + dA[u].x) * o0;
            rr[u].y = (sA[u].y + dA[u].y) * o1;
            rr[u].z = (sA[u].z + dA[u].z) * o2;
            rr[u].w = (sA[u].w + dA[u].w) * o3;
        }

        __builtin_amdgcn_s_barrier();        // raw barrier: NO vmcnt(0) drain

        #pragma unroll
        for (int u = 0; u < 4; ++u) {        // block-wide 16KB store burst
            const int idx = (c * CHUNK + u * NT + t) * 4;
            STORE4(ob + idx, rr[u].x, rr[u].y, rr[u].z, rr[u].w);
        }

        if (c + 1 < NCH) {
            #pragma unroll
            for (int u = 0; u < 4; ++u) { sA[u] = sN[u]; dA[u] = dN[u]; }
        }
    }

    // ---- divergent tail (904 f4), barrier-free ----
    for (int k = NCH * CHUNK + t; k < NF4; k += NT) {
        const int i0 = 4 * k;
        const f4v s0 = *(const f4v*)(sb + i0);
        const f4v d0 = *(const f4v*)(db + i0);
        float o0, o1, o2, o3;
        OBS4(i0 % HW, o0, o1, o2, o3);
        STORE4(ob + i0, (s0.x + d0.x) * o0, (s0.y + d0.y) * o1,
                        (s0.z + d0.z) * o2, (s0.w + d0.w) * o3);
    }
#undef OBS4
#undef STORE4
}

extern "C" void kernel_launch(void* const* d_in, const int* in_sizes, int n_in,
                              void* d_out, int out_size, void* d_ws, size_t ws_size,
                              hipStream_t stream) {
    const float* sta  = (const float*)d_in[0];
    const float* dyn  = (const float*)d_in[1];
    const float* obst = (const float*)d_in[2];
    const float* ocur = (const float*)d_in[3];
    const float* omem = (const float*)d_in[4];
    const float* pvis = (const float*)d_in[5];
    const float* atgt = (const float*)d_in[6];
    const float* ptgt = (const float*)d_in[7];
    const float* lead = (const float*)d_in[8];
    const float* foll = (const float*)d_in[9];
    const int*   rots = (const int*)d_in[10];
    float* out = (float*)d_out;

    const int nb = in_sizes[10];             // batch count (1024)

    hipLaunchKernelGGL(env_embed, dim3(5 * nb), dim3(NT), 0, stream,
                       sta, dyn, obst, ocur, omem, pvis, atgt, ptgt,
                       lead, foll, rots, out, nb);
}